// Round 15
// baseline (267.623 us; speedup 1.0000x reference)
//
#include <hip/hip_runtime.h>
#include <cstdint>

// Problem constants (match reference)
#define N_PTS 100000
#define DIN   40
#define DH    30
#define DOUT  10
#define NB    10000
#define NNB   64
#define NR    10
#define EPSF  1e-5f

// v_rcp_f32 + one Newton step: ~fp32-exact (R6: raw rcp on pivots -> 8x
// worse absmax).
__device__ __forceinline__ float rcp_nr(float x) {
    float r = __builtin_amdgcn_rcpf(x);
    return r * (2.0f - x * r);
}

// Raw v_sqrt_f32 (no libm fixup; args in [0, ~200]).
__device__ __forceinline__ float fast_sqrt(float x) {
    return __builtin_amdgcn_sqrtf(x);
}

// v_readlane broadcast (VALU pipe, not DS crossbar: R3). Lane index may be a
// RUNTIME wave-uniform value (SGPR operand); only ARRAY indices must be
// compile-time (R2).
//
// NUMERICS INVARIANT (R12): ~200/10k batches have exactly-duplicated
// neighbors; dj (dot chain) must be BITWISE EQUAL to sq (norm chain) ->
// single sequential fma chain over d=0..9 in Build. Update ORDER of
// independent columns is free; per-column arithmetic is not.
//
// R14 lesson: with an ~85-float live set the allocator ALWAYS parks ar[] in
// AGPRs (~60 arch granted at every launch-bounds setting) and readlane can't
// source AGPRs -> x2.2 instruction inflation (measured 16.8k cy-equiv vs
// 7.8k source). R15: 2 waves per system, odd/even column split -> arh[32],
// live ~55 floats -> fits the 60-arch grant, no parking, no copy tax.
__device__ __forceinline__ float lane_bcast(float x, int lane) {
    return __int_as_float(__builtin_amdgcn_readlane(__float_as_int(x), lane));
}

// Rank-1 update, arch-constrained (R14: kept issue efficiency high).
// Bit-identical to fmaf(-m, p, a).
__device__ __forceinline__ void fma_arch(float& a, const float negm, const float p) {
    asm("v_fmac_f32 %0, %2, %1" : "+v"(a) : "v"(negm), "s"(p));
}

// ---------------------------------------------------------------------------
// Kernel 1: MLP embedding. One point per thread; weights staged in LDS.
// ---------------------------------------------------------------------------
__global__ __launch_bounds__(256) void mlp_kernel(
    const float* __restrict__ x,
    const float* __restrict__ W1, const float* __restrict__ b1, const float* __restrict__ a1p,
    const float* __restrict__ W2, const float* __restrict__ b2, const float* __restrict__ a2p,
    float* __restrict__ emb)
{
    __shared__ float sW1[DH * DIN];
    __shared__ float sW2[DOUT * DH];
    __shared__ float sb1[DH];
    __shared__ float sb2[DOUT];
    for (int i = threadIdx.x; i < DH * DIN; i += 256) sW1[i] = W1[i];
    for (int i = threadIdx.x; i < DOUT * DH; i += 256) sW2[i] = W2[i];
    if (threadIdx.x < DH)   sb1[threadIdx.x] = b1[threadIdx.x];
    if (threadIdx.x < DOUT) sb2[threadIdx.x] = b2[threadIdx.x];
    const float a1 = a1p[0], a2 = a2p[0];
    __syncthreads();

    const int n = blockIdx.x * 256 + threadIdx.x;
    if (n >= N_PTS) return;

    float xv[DIN];
    const float4* xp = reinterpret_cast<const float4*>(x + (size_t)n * DIN);
#pragma unroll
    for (int q = 0; q < DIN / 4; ++q) {
        float4 v = xp[q];
        xv[4*q+0] = v.x; xv[4*q+1] = v.y; xv[4*q+2] = v.z; xv[4*q+3] = v.w;
    }

    float h[DH];
#pragma unroll
    for (int i = 0; i < DH; ++i) {
        float acc = sb1[i];
#pragma unroll
        for (int j = 0; j < DIN; ++j) acc = fmaf(xv[j], sW1[i * DIN + j], acc);
        h[i] = acc > 0.0f ? acc : a1 * acc;
    }

    float* eo = emb + (size_t)n * DOUT;
#pragma unroll
    for (int d = 0; d < DOUT; ++d) {
        float acc = sb2[d];
#pragma unroll
        for (int i = 0; i < DH; ++i) acc = fmaf(h[i], sW2[d * DH + i], acc);
        eo[d] = acc > 0.0f ? acc : a2 * acc;
    }
}

// ---------------------------------------------------------------------------
// 2-wave split solve. Lane i = row i on BOTH waves; wave w owns columns j
// with (j&1)==w at local index h=j>>1 (arh[32]), plus RHS columns r=2q+w
// (wave0 additionally owns the kc column as local 5).
// ---------------------------------------------------------------------------

// Build owned column j = 2H + w. dj: single sequential fma chain (invariant).
template<int H>
struct Build2 {
    static __device__ __forceinline__ void run(float (&arh)[32], const float (&xn)[DOUT],
                                               const float sq, const int lane, const int w) {
        const int j = 2 * H + w;                 // wave-uniform runtime lane
        float px[DOUT];
#pragma unroll
        for (int d = 0; d < DOUT; ++d) px[d] = lane_bcast(xn[d], j);
        float dj = 0.0f;
#pragma unroll
        for (int d = 0; d < DOUT; ++d) dj = fmaf(px[d], xn[d], dj);
        const float sqj = lane_bcast(sq, j);
        const float d2  = sq + sqj - 2.0f * dj;
        const float kij = __expf(-fast_sqrt(fmaxf(d2, 0.0f)));
        arh[H] = (j == lane) ? (1.0f + EPSF) : kij;
        Build2<H + 1>::run(arh, xn, sq, lane, w);
    }
};
template<>
struct Build2<32> {
    static __device__ __forceinline__ void run(float (&)[32], const float (&)[DOUT],
                                               float, int, int) {}
};

// Batched column-update group over local indices [H0, H0+CNT)
template<int K, int H0, int CNT>
struct GrpH {
    static __device__ __forceinline__ void run(float (&arh)[32], const float negm) {
        float p[CNT];
#pragma unroll
        for (int t = 0; t < CNT; ++t) p[t] = lane_bcast(arh[H0 + t], K);
#pragma unroll
        for (int t = 0; t < CNT; ++t) fma_arch(arh[H0 + t], negm, p[t]);
    }
};
template<int K, int H0>
struct SufH {
    static __device__ __forceinline__ void run(float (&arh)[32], const float negm) {
        constexpr int REM = 32 - H0;
        constexpr int CNT = (REM < 8) ? REM : 8;
        GrpH<K, H0, CNT>::run(arh, negm);
        if constexpr (H0 + CNT < 32) SufH<K, H0 + CNT>::run(arh, negm);
    }
};

// RHS update, N owned columns
template<int K, int N>
struct RrUpd {
    static __device__ __forceinline__ void run(float (&rrh)[6], const float negm) {
        float pr[N];
#pragma unroll
        for (int q = 0; q < N; ++q) pr[q] = lane_bcast(rrh[q], K);
#pragma unroll
        for (int q = 0; q < N; ++q) fma_arch(rrh[q], negm, pr[q]);
    }
};

// Gauss-Jordan step K, 2-wave. Owner (w==K&1) computes m and posts to LDS
// (buffer K&1: consecutive steps alternate; re-write of a buffer is always
// separated from its readers by the intervening barrier). Non-owner updates
// col K+1 FIRST, then preps its own next pivot inverse (2-step pipeline).
template<int K>
struct GJ2 {
    static __device__ __forceinline__ void run(float (&arh)[32], float (&rrh)[6],
                                               float& mydiag, float& inv_own,
                                               const int lane, const int w,
                                               float* lds_m) {
        constexpr int OWNER = K & 1;
        constexpr int HK    = K >> 1;
        float m = 0.0f;
        if (w == OWNER) {                        // wave-uniform branch
            m      = (lane == K) ? 0.0f : arh[HK] * inv_own;
            mydiag = (lane == K) ? arh[HK] : mydiag;  // col K final at step K
            lds_m[OWNER * 64 + lane] = m;
        }
        __syncthreads();
        if (w != OWNER) m = lds_m[OWNER * 64 + lane];
        const float negm = -m;

        if (w == OWNER) {
            // owned cols j = K+2, K+4, ... -> h = HK+1 .. 31
            if constexpr (HK + 1 <= 31) SufH<K, HK + 1>::run(arh, negm);
            RrUpd<K, (OWNER == 0 ? 6 : 5)>::run(rrh, negm);
        } else {
            constexpr int HN = (K + 1) >> 1;     // col K+1 local index
            if constexpr (HN <= 31) {
                {   // col K+1 first, then prep inv for step K+1 (we own it)
                    const float p = lane_bcast(arh[HN], K);
                    fma_arch(arh[HN], negm, p);
                }
                inv_own = rcp_nr(lane_bcast(arh[HN], K + 1));
                if constexpr (HN + 1 <= 31) SufH<K, HN + 1>::run(arh, negm);
            }
            RrUpd<K, (OWNER == 0 ? 5 : 6)>::run(rrh, negm);
        }
        GJ2<K + 1>::run(arh, rrh, mydiag, inv_own, lane, w, lds_m);
    }
};
template<>
struct GJ2<NNB> {
    static __device__ __forceinline__ void run(float (&)[32], float (&)[6],
                                               float&, float&, int, int, float*) {}
};

// ---------------------------------------------------------------------------
// Kernel 2: 128 threads = 2 waves = ONE system per block.
// (128, 4): cap 128 -- allocator grants ~60 arch (R7/R10/R13/R14), and the
// split live set (~55) now FITS: no AGPR parking, no copy tax.
// ---------------------------------------------------------------------------
__global__ __launch_bounds__(128, 4) void solve_kernel(
    const float* __restrict__ emb,
    const int* __restrict__ bidx,
    const int* __restrict__ bnn,
    const float* __restrict__ tnn_g,
    float* __restrict__ pred,   // [NB][NR]
    float* __restrict__ var,    // [NB]
    float* __restrict__ part)   // [NB][NR] sigma_sq partials
{
    __shared__ float lds_m[2 * 64];
    __shared__ float lds_md[64];

    const int w    = threadIdx.x >> 6;   // 0..1
    const int lane = threadIdx.x & 63;
    const int b    = blockIdx.x;

    // Row embedding (identical loads on both waves)
    const int idx = bnn[b * NNB + lane];
    float xn[DOUT];
    {
        const float2* ep = reinterpret_cast<const float2*>(emb + (size_t)idx * DOUT);
#pragma unroll
        for (int q = 0; q < DOUT / 2; ++q) { float2 v = ep[q]; xn[2*q] = v.x; xn[2*q+1] = v.y; }
    }
    const int bi = bidx[b];
    float sq = 0.0f, dotb = 0.0f, sqb = 0.0f;
#pragma unroll
    for (int d = 0; d < DOUT; ++d) {
        const float xbd = emb[(size_t)bi * DOUT + d];
        sq   = fmaf(xn[d], xn[d], sq);
        dotb = fmaf(xbd, xn[d], dotb);
        sqb  = fmaf(xbd, xbd, sqb);
    }
    const float d2c = sqb + sq - 2.0f * dotb;
    const float kc  = __expf(-fast_sqrt(fmaxf(d2c, 0.0f)));

    // Build owned columns (32 per wave)
    float arh[32];
    Build2<0>::run(arh, xn, sq, lane, w);

    // RHS: wave w owns r = 2q+w (q=0..4); wave0 also owns the kc column.
    float rrh[6];
    {
        const float2* tp = reinterpret_cast<const float2*>(
            tnn_g + ((size_t)b * NNB + lane) * NR);
#pragma unroll
        for (int q = 0; q < 5; ++q) { float2 v = tp[q]; rrh[q] = (w == 0) ? v.x : v.y; }
    }
    rrh[5] = (w == 0) ? kc : 0.0f;

    float mydiag  = 1.0f;
    float inv_own = 1.0f;
    if (w == 0) inv_own = rcp_nr(lane_bcast(arh[0], 0));   // step-0 pivot

    GJ2<0>::run(arh, rrh, mydiag, inv_own, lane, w, lds_m);

    // Cross the diagonal: wave w holds mydiag for lanes of parity w.
    if ((lane & 1) == w) lds_md[lane] = mydiag;
    __syncthreads();
    const float dinv = rcp_nr(lds_md[lane]);

    // Targets for owned r's (pairs, select half)
    float tnq[5];
    {
        const float2* tp = reinterpret_cast<const float2*>(
            tnn_g + ((size_t)b * NNB + lane) * NR);
#pragma unroll
        for (int q = 0; q < 5; ++q) { float2 v = tp[q]; tnq[q] = (w == 0) ? v.x : v.y; }
    }

    // Outputs (butterfly reduce within each wave; r = 2q + w)
    float pv[5], sg[5];
#pragma unroll
    for (int q = 0; q < 5; ++q) {
        const float xr = rrh[q] * dinv;
        pv[q] = kc * xr;
        sg[q] = tnq[q] * xr;
    }
    float vv = (w == 0) ? kc * (rrh[5] * dinv) : 0.0f;
#pragma unroll
    for (int off = 32; off > 0; off >>= 1) {
#pragma unroll
        for (int q = 0; q < 5; ++q) {
            pv[q] += __shfl_xor(pv[q], off);
            sg[q] += __shfl_xor(sg[q], off);
        }
        vv += __shfl_xor(vv, off);
    }
    if (lane == 0) {
#pragma unroll
        for (int q = 0; q < 5; ++q) {
            pred[b * NR + 2 * q + w] = pv[q];
            part[b * NR + 2 * q + w] = sg[q];
        }
        if (w == 0) var[b] = 1.0f - vv;
    }
}

// ---------------------------------------------------------------------------
// Kernel 3: deterministic reduction of sigma_sq partials (fixed order)
// ---------------------------------------------------------------------------
__global__ __launch_bounds__(256) void reduce_kernel(
    const float* __restrict__ part, float* __restrict__ sig)
{
    float acc[NR];
#pragma unroll
    for (int r = 0; r < NR; ++r) acc[r] = 0.0f;
    for (int b = threadIdx.x; b < NB; b += 256) {
#pragma unroll
        for (int r = 0; r < NR; ++r) acc[r] += part[b * NR + r];
    }
#pragma unroll
    for (int off = 32; off > 0; off >>= 1) {
#pragma unroll
        for (int r = 0; r < NR; ++r) acc[r] += __shfl_xor(acc[r], off);
    }
    __shared__ float s[4][NR];
    const int w = threadIdx.x >> 6, l = threadIdx.x & 63;
    if (l == 0) {
#pragma unroll
        for (int r = 0; r < NR; ++r) s[w][r] = acc[r];
    }
    __syncthreads();
    if (threadIdx.x == 0) {
        const float scale = 1.0f / ((float)NB * (float)NNB);
#pragma unroll
        for (int r = 0; r < NR; ++r)
            sig[r] = (s[0][r] + s[1][r] + s[2][r] + s[3][r]) * scale;
    }
}

// ---------------------------------------------------------------------------
extern "C" void kernel_launch(void* const* d_in, const int* in_sizes, int n_in,
                              void* d_out, int out_size, void* d_ws, size_t ws_size,
                              hipStream_t stream)
{
    const float* x    = (const float*)d_in[0];
    const int*   bidx = (const int*)  d_in[1];
    const int*   bnn  = (const int*)  d_in[2];
    // d_in[3] = batch_targets: unused by the reference computation
    const float* tnn  = (const float*)d_in[4];
    const float* W1   = (const float*)d_in[5];
    const float* b1   = (const float*)d_in[6];
    const float* a1   = (const float*)d_in[7];
    const float* W2   = (const float*)d_in[8];
    const float* b2   = (const float*)d_in[9];
    const float* a2   = (const float*)d_in[10];

    float* out  = (float*)d_out;
    float* pred = out;                 // 100000
    float* var  = out + NB * NR;       // 10000
    float* sig  = out + NB * NR + NB;  // 10

    float* emb  = (float*)d_ws;        // N_PTS*DOUT floats (4 MB)
    float* part = emb + (size_t)N_PTS * DOUT; // NB*NR floats (400 KB)

    mlp_kernel<<<(N_PTS + 255) / 256, 256, 0, stream>>>(x, W1, b1, a1, W2, b2, a2, emb);
    solve_kernel<<<NB, 128, 0, stream>>>(emb, bidx, bnn, tnn, pred, var, part);
    reduce_kernel<<<1, 256, 0, stream>>>(part, sig);
}

// Round 16
// 190.736 us; speedup vs baseline: 1.4031x; 1.4031x over previous
//
#include <hip/hip_runtime.h>
#include <cstdint>

// Problem constants (match reference)
#define N_PTS 100000
#define DIN   40
#define DH    30
#define DOUT  10
#define NB    10000
#define NNB   64
#define NR    10
#define EPSF  1e-5f

// v_rcp_f32 + one Newton step: ~fp32-exact (R6: raw rcp on pivots -> 8x
// worse absmax).
__device__ __forceinline__ float rcp_nr(float x) {
    float r = __builtin_amdgcn_rcpf(x);
    return r * (2.0f - x * r);
}

// Raw v_sqrt_f32 (no libm fixup; args in [0, ~200]).
__device__ __forceinline__ float fast_sqrt(float x) {
    return __builtin_amdgcn_sqrtf(x);
}

// v_readlane broadcast (VALU pipe, not DS crossbar: R3 lesson).
//
// NUMERICS INVARIANT (R12): ~200/10k batches have exactly-duplicated
// neighbors; dj (dot chain) must be BITWISE EQUAL to sq (norm chain) ->
// single sequential fma chain over d=0..9 in Build. Update ORDER of
// independent columns is free; per-column arithmetic is not.
//
// ALLOCATOR MODEL (R3-R15 consolidated): the arch/AGPR split follows the
// PRESSURE PROFILE, not the launch-bounds cap. R3's LU (flat ~90 live to
// the end) got 128 arch clean; GJ's decaying profile (ar[j] dies at step j)
// makes LLVM park long-lived tail columns in AGPRs -- and readlane can't
// source AGPRs -> ~4-instr round-trip per touch = x2.1 measured inflation.
// R16 fix: keep-alive asm on ALL ar[] elements AFTER the solve flattens the
// profile to LU-like, steering the heuristic back to arch. Zero instructions,
// zero arithmetic change.
__device__ __forceinline__ float lane_bcast(float x, int lane) {
    return __int_as_float(__builtin_amdgcn_readlane(__float_as_int(x), lane));
}

// Rank-1 update, arch-constrained (R14: +13us vs plain fmaf).
// Bit-identical to fmaf(-m, p, a).
__device__ __forceinline__ void fma_arch(float& a, const float negm, const float p) {
    asm("v_fmac_f32 %0, %2, %1" : "+v"(a) : "v"(negm), "s"(p));
}

// ---------------------------------------------------------------------------
// Kernel 1: MLP embedding. One point per thread; weights staged in LDS.
// ---------------------------------------------------------------------------
__global__ __launch_bounds__(256) void mlp_kernel(
    const float* __restrict__ x,
    const float* __restrict__ W1, const float* __restrict__ b1, const float* __restrict__ a1p,
    const float* __restrict__ W2, const float* __restrict__ b2, const float* __restrict__ a2p,
    float* __restrict__ emb)
{
    __shared__ float sW1[DH * DIN];
    __shared__ float sW2[DOUT * DH];
    __shared__ float sb1[DH];
    __shared__ float sb2[DOUT];
    for (int i = threadIdx.x; i < DH * DIN; i += 256) sW1[i] = W1[i];
    for (int i = threadIdx.x; i < DOUT * DH; i += 256) sW2[i] = W2[i];
    if (threadIdx.x < DH)   sb1[threadIdx.x] = b1[threadIdx.x];
    if (threadIdx.x < DOUT) sb2[threadIdx.x] = b2[threadIdx.x];
    const float a1 = a1p[0], a2 = a2p[0];
    __syncthreads();

    const int n = blockIdx.x * 256 + threadIdx.x;
    if (n >= N_PTS) return;

    float xv[DIN];
    const float4* xp = reinterpret_cast<const float4*>(x + (size_t)n * DIN); // 160B rows
#pragma unroll
    for (int q = 0; q < DIN / 4; ++q) {
        float4 v = xp[q];
        xv[4*q+0] = v.x; xv[4*q+1] = v.y; xv[4*q+2] = v.z; xv[4*q+3] = v.w;
    }

    float h[DH];
#pragma unroll
    for (int i = 0; i < DH; ++i) {
        float acc = sb1[i];
#pragma unroll
        for (int j = 0; j < DIN; ++j) acc = fmaf(xv[j], sW1[i * DIN + j], acc);
        h[i] = acc > 0.0f ? acc : a1 * acc;
    }

    float* eo = emb + (size_t)n * DOUT;
#pragma unroll
    for (int d = 0; d < DOUT; ++d) {
        float acc = sb2[d];
#pragma unroll
        for (int i = 0; i < DH; ++i) acc = fmaf(h[i], sW2[d * DH + i], acc);
        eo[d] = acc > 0.0f ? acc : a2 * acc;
    }
}

// ---------------------------------------------------------------------------
// Template-recursive solve blocks: every array index AND readlane lane index
// is a compile-time constant (R2: runtime k -> scratch; R3: __shfl -> DS).
// ---------------------------------------------------------------------------

// Build row `lane` of Kplus = exp(-dist) + eps*I.
// Readlanes batched; dj is a SINGLE sequential fma chain (invariant above).
template<int J>
struct Build {
    static __device__ __forceinline__ void run(float (&ar)[NNB], const float (&xn)[DOUT],
                                               const float sq, const int lane) {
        float px[DOUT];
#pragma unroll
        for (int d = 0; d < DOUT; ++d) px[d] = lane_bcast(xn[d], J);
        float dj = 0.0f;
#pragma unroll
        for (int d = 0; d < DOUT; ++d) dj = fmaf(px[d], xn[d], dj);
        const float sqj = lane_bcast(sq, J);
        const float d2  = sq + sqj - 2.0f * dj;
        const float kij = __expf(-fast_sqrt(fmaxf(d2, 0.0f)));
        ar[J] = (J == lane) ? (1.0f + EPSF) : kij;   // exact diag + jitter
        Build<J + 1>::run(ar, xn, sq, lane);
    }
};
template<>
struct Build<NNB> {
    static __device__ __forceinline__ void run(float (&)[NNB], const float (&)[DOUT],
                                               float, int) {}
};

// Batched rank-1 update group: CNT readlanes, then CNT arch-constrained fmacs.
template<int K, int J, int CNT>
struct Grp {
    static __device__ __forceinline__ void run(float (&ar)[NNB], const float negm) {
        float p[CNT];
#pragma unroll
        for (int t = 0; t < CNT; ++t) p[t] = lane_bcast(ar[J + t], K);
#pragma unroll
        for (int t = 0; t < CNT; ++t) fma_arch(ar[J + t], negm, p[t]);
    }
};

// Drive groups of 8 over the suffix [J, NNB)
template<int K, int J>
struct Suffix {
    static __device__ __forceinline__ void run(float (&ar)[NNB], const float negm) {
        constexpr int REM = NNB - J;
        constexpr int CNT = (REM < 8) ? REM : 8;
        Grp<K, J, CNT>::run(ar, negm);
        if constexpr (J + CNT < NNB) Suffix<K, J + CNT>::run(ar, negm);
    }
};

// Software-pipelined Gauss-Jordan step K (R10/R13/R14 semantics exactly).
template<int K>
struct GJ {
    static __device__ __forceinline__ void run(float (&ar)[NNB], float (&rr)[NR + 1],
                                               float& mydiag, const int lane,
                                               const float inv) {
        const float m    = (lane == K) ? 0.0f : ar[K] * inv;
        const float negm = -m;
        mydiag = (lane == K) ? ar[K] : mydiag;    // column K never touched again

        // Column K+1 first (pivot-row value from lane K, pre-update)
        {
            const float p = lane_bcast(ar[K + 1], K);
            fma_arch(ar[K + 1], negm, p);
        }
        // Next pivot chain launches early: lane K+1's ar[K+1] is now final
        const float inv_next = rcp_nr(lane_bcast(ar[K + 1], K + 1));

        // Bulk updates, batched 8-wide; overlap inv_next's latency
        if constexpr (K + 2 < NNB) Suffix<K, K + 2>::run(ar, negm);

        // RHS: all 11 readlanes, then all 11 constrained fmacs
        {
            float pr[NR + 1];
#pragma unroll
            for (int r = 0; r <= NR; ++r) pr[r] = lane_bcast(rr[r], K);
#pragma unroll
            for (int r = 0; r <= NR; ++r) fma_arch(rr[r], negm, pr[r]);
        }

        GJ<K + 1>::run(ar, rr, mydiag, lane, inv_next);
    }
};
// Last step: only the RHS remains.
template<>
struct GJ<NNB - 1> {
    static __device__ __forceinline__ void run(float (&ar)[NNB], float (&rr)[NR + 1],
                                               float& mydiag, const int lane,
                                               const float inv) {
        constexpr int K  = NNB - 1;
        const float m    = (lane == K) ? 0.0f : ar[K] * inv;
        const float negm = -m;
        mydiag = (lane == K) ? ar[K] : mydiag;
        float pr[NR + 1];
#pragma unroll
        for (int r = 0; r <= NR; ++r) pr[r] = lane_bcast(rr[r], K);
#pragma unroll
        for (int r = 0; r <= NR; ++r) fma_arch(rr[r], negm, pr[r]);
    }
};

// ---------------------------------------------------------------------------
// Kernel 2: one wave per batch item, 2 items per 128-thread block.
// (128, 1): loose cap (512) so a FLAT ~115-reg arch allocation fits.
// The post-GJ keep-alives flatten the pressure profile (see model above).
// ---------------------------------------------------------------------------
__global__ __launch_bounds__(128, 1) void solve_kernel(
    const float* __restrict__ emb,
    const int* __restrict__ bidx,
    const int* __restrict__ bnn,
    const float* __restrict__ tnn_g,
    float* __restrict__ pred,   // [NB][NR]
    float* __restrict__ var,    // [NB]
    float* __restrict__ part)   // [NB][NR] sigma_sq partials
{
    const int wave = threadIdx.x >> 6;        // 0..1
    const int lane = threadIdx.x & 63;
    const int b    = blockIdx.x * 2 + wave;   // NB = 5000*2, exact

    // Gather this lane's neighbor embedding (10 floats, 8B-aligned rows)
    const int idx = bnn[b * NNB + lane];
    float xn[DOUT];
    {
        const float2* ep = reinterpret_cast<const float2*>(emb + (size_t)idx * DOUT);
#pragma unroll
        for (int q = 0; q < DOUT / 2; ++q) { float2 v = ep[q]; xn[2*q] = v.x; xn[2*q+1] = v.y; }
    }
    // Center embedding (same for all lanes; broadcast through cache)
    const int bi = bidx[b];
    float sq = 0.0f, dotb = 0.0f, sqb = 0.0f;
#pragma unroll
    for (int d = 0; d < DOUT; ++d) {
        const float xbd = emb[(size_t)bi * DOUT + d];
        sq   = fmaf(xn[d], xn[d], sq);
        dotb = fmaf(xbd, xn[d], dotb);
        sqb  = fmaf(xbd, xbd, sqb);
    }
    const float d2c = sqb + sq - 2.0f * dotb;
    const float kc  = __expf(-fast_sqrt(fmaxf(d2c, 0.0f)));

    // K matrix row (registers, static indices only)
    float ar[NNB];
    Build<0>::run(ar, xn, sq, lane);

    // RHS row: [targets(10), Kcross]. tn reloaded at the end (pressure).
    float rr[NR + 1];
    {
        const float2* tp = reinterpret_cast<const float2*>(
            tnn_g + (size_t)b * NNB * NR + (size_t)lane * NR);
#pragma unroll
        for (int q = 0; q < NR / 2; ++q) { float2 v = tp[q]; rr[2*q] = v.x; rr[2*q+1] = v.y; }
    }
    rr[NR] = kc;

    // Prologue of the pipeline: step-0 pivot chain
    const float inv0 = rcp_nr(lane_bcast(ar[0], 0));
    float mydiag = 1.0f;
    GJ<0>::run(ar, rr, mydiag, lane, inv0);

    // R16: keep-alive on every ar element -- extends all column live ranges
    // to this point, flattening the pressure profile to LU-like (R3's clean
    // 128-arch case). Empty asm: zero instructions, zero arithmetic change.
#pragma unroll
    for (int j = 0; j < NNB; ++j) asm volatile("" :: "v"(ar[j]));

    const float dinv = rcp_nr(mydiag);   // x_i = rr_i * dinv (A now diagonal)

    // Reload targets for sigma_sq partials
    float tn[NR];
    {
        const float2* tp = reinterpret_cast<const float2*>(
            tnn_g + (size_t)b * NNB * NR + (size_t)lane * NR);
#pragma unroll
        for (int q = 0; q < NR / 2; ++q) { float2 v = tp[q]; tn[2*q] = v.x; tn[2*q+1] = v.y; }
    }

    // Outputs: predictions, variance, sigma_sq partials (wave butterfly reduce)
    float pv[NR], sg[NR];
#pragma unroll
    for (int r = 0; r < NR; ++r) {
        const float xr = rr[r] * dinv;     // coeffs[lane][r]
        pv[r] = kc * xr;
        sg[r] = tn[r] * xr;
    }
    float vv = kc * rr[NR] * dinv;         // kc * kc_solve[lane]
#pragma unroll
    for (int off = 32; off > 0; off >>= 1) {
#pragma unroll
        for (int r = 0; r < NR; ++r) {
            pv[r] += __shfl_xor(pv[r], off);
            sg[r] += __shfl_xor(sg[r], off);
        }
        vv += __shfl_xor(vv, off);
    }
    if (lane == 0) {
#pragma unroll
        for (int r = 0; r < NR; ++r) {
            pred[b * NR + r] = pv[r];
            part[b * NR + r] = sg[r];
        }
        var[b] = 1.0f - vv;
    }
}

// ---------------------------------------------------------------------------
// Kernel 3: deterministic reduction of sigma_sq partials (fixed order)
// ---------------------------------------------------------------------------
__global__ __launch_bounds__(256) void reduce_kernel(
    const float* __restrict__ part, float* __restrict__ sig)
{
    float acc[NR];
#pragma unroll
    for (int r = 0; r < NR; ++r) acc[r] = 0.0f;
    for (int b = threadIdx.x; b < NB; b += 256) {
#pragma unroll
        for (int r = 0; r < NR; ++r) acc[r] += part[b * NR + r];
    }
#pragma unroll
    for (int off = 32; off > 0; off >>= 1) {
#pragma unroll
        for (int r = 0; r < NR; ++r) acc[r] += __shfl_xor(acc[r], off);
    }
    __shared__ float s[4][NR];
    const int w = threadIdx.x >> 6, l = threadIdx.x & 63;
    if (l == 0) {
#pragma unroll
        for (int r = 0; r < NR; ++r) s[w][r] = acc[r];
    }
    __syncthreads();
    if (threadIdx.x == 0) {
        const float scale = 1.0f / ((float)NB * (float)NNB);
#pragma unroll
        for (int r = 0; r < NR; ++r)
            sig[r] = (s[0][r] + s[1][r] + s[2][r] + s[3][r]) * scale;
    }
}

// ---------------------------------------------------------------------------
extern "C" void kernel_launch(void* const* d_in, const int* in_sizes, int n_in,
                              void* d_out, int out_size, void* d_ws, size_t ws_size,
                              hipStream_t stream)
{
    const float* x    = (const float*)d_in[0];
    const int*   bidx = (const int*)  d_in[1];
    const int*   bnn  = (const int*)  d_in[2];
    // d_in[3] = batch_targets: unused by the reference computation
    const float* tnn  = (const float*)d_in[4];
    const float* W1   = (const float*)d_in[5];
    const float* b1   = (const float*)d_in[6];
    const float* a1   = (const float*)d_in[7];
    const float* W2   = (const float*)d_in[8];
    const float* b2   = (const float*)d_in[9];
    const float* a2   = (const float*)d_in[10];

    float* out  = (float*)d_out;
    float* pred = out;                 // 100000
    float* var  = out + NB * NR;       // 10000
    float* sig  = out + NB * NR + NB;  // 10

    float* emb  = (float*)d_ws;        // N_PTS*DOUT floats (4 MB)
    float* part = emb + (size_t)N_PTS * DOUT; // NB*NR floats (400 KB)

    mlp_kernel<<<(N_PTS + 255) / 256, 256, 0, stream>>>(x, W1, b1, a1, W2, b2, a2, emb);
    solve_kernel<<<NB / 2, 128, 0, stream>>>(emb, bidx, bnn, tnn, pred, var, part);
    reduce_kernel<<<1, 256, 0, stream>>>(part, sig);
}